// Round 1
// baseline (202.614 us; speedup 1.0000x reference)
//
#include <hip/hip_runtime.h>
#include <hip/hip_bf16.h>

// ---- problem constants ----
#define NN 25000
#define PP 100000
#define TT 4
#define DD 128
#define LEAKY 0.001f

#define PB 32          // propers per block (8 waves x 4 propers)
#define ROWS 128       // PB * TT rows of the MLP per block

typedef __bf16 bf16;
typedef __bf16 bf16x8 __attribute__((ext_vector_type(8)));
typedef float  f32x4  __attribute__((ext_vector_type(4)));

// ---- workspace layout (bytes) ----
#define OFF_W0SW  0u                    // 128 chunks * 1KB (fragment order)
#define OFF_W1SW  131072u               // 32 chunks * 1KB
#define OFF_W2SW  163840u               // 32 chunks * 1KB
#define OFF_W3SW  196608u               // 4 chunks * 1KB
#define OFF_WTB   200704u               // Wt[t][j] = t*W0[512]+b0, 4*128 bf16
#define OFF_W5B   201728u               // W0 rows 513..515 as bf16
#define OFF_E     202496u               // 4 tables [NN][128] bf16 = 25,600,000 B
#define WS_END    25802496u

// prep work partition (thread counts)
#define PR_W0SW  65536
#define PR_W1SW  16384
#define PR_W2SW  16384
#define PR_W3SW  2048
#define PR_WTB   512
#define PR_W5B   384
#define PR_COPY4 75000
#define PR_TOTAL (PR_W0SW + PR_W1SW + PR_W2SW + PR_W3SW + PR_WTB + PR_W5B + PR_COPY4)

__global__ __launch_bounds__(256) void prep_kernel(
    const float* __restrict__ W0, const float* __restrict__ W1,
    const float* __restrict__ W2, const float* __restrict__ W3,
    const float* __restrict__ answer, const float* __restrict__ tvec,
    const float* __restrict__ b0,
    bf16* __restrict__ W0sw, bf16* __restrict__ W1sw, bf16* __restrict__ W2sw,
    bf16* __restrict__ W3sw, bf16* __restrict__ WtB, bf16* __restrict__ W5B,
    float* __restrict__ out)
{
    int idx = blockIdx.x * 256 + threadIdx.x;
    if (idx < PR_W0SW) {
        int j = idx & 7, lane = (idx >> 3) & 63, c = idx >> 9;
        int fr = lane & 15, quad = lane >> 4;
        int kc = c & 15, iwv = c >> 4;
        int k = kc * 32 + quad * 8 + j;
        W0sw[idx] = (bf16)W0[k * 128 + iwv * 16 + fr];
        return;
    }
    idx -= PR_W0SW;
    if (idx < PR_W1SW) {
        int j = idx & 7, lane = (idx >> 3) & 63, c = idx >> 9;
        int fr = lane & 15, quad = lane >> 4;
        int kc = c & 3, nt = c >> 2;
        int k = kc * 32 + quad * 8 + j;
        W1sw[idx] = (bf16)W1[k * 128 + nt * 16 + fr];
        return;
    }
    idx -= PR_W1SW;
    if (idx < PR_W2SW) {
        int j = idx & 7, lane = (idx >> 3) & 63, c = idx >> 9;
        int fr = lane & 15, quad = lane >> 4;
        int kc = c & 3, nt = c >> 2;
        int k = kc * 32 + quad * 8 + j;
        W2sw[idx] = (bf16)W2[k * 128 + nt * 16 + fr];
        return;
    }
    idx -= PR_W2SW;
    if (idx < PR_W3SW) {
        int j = idx & 7, lane = (idx >> 3) & 63, kc = idx >> 9;
        int fr = lane & 15, quad = lane >> 4;
        int k = kc * 32 + quad * 8 + j;
        W3sw[idx] = (fr < 2) ? (bf16)W3[k * 2 + fr] : (bf16)0.0f;
        return;
    }
    idx -= PR_W3SW;
    if (idx < PR_WTB) {                 // Wt[t][j] = tvec[t]*W0[512][j] + b0[j]
        int t = idx >> 7, j = idx & 127;
        WtB[idx] = (bf16)(tvec[t] * W0[512 * 128 + j] + b0[j]);
        return;
    }
    idx -= PR_WTB;
    if (idx < PR_W5B) {                 // W0 rows 513,514,515 -> bf16
        W5B[idx] = (bf16)W0[(513 + (idx >> 7)) * 128 + (idx & 127)];
        return;
    }
    idx -= PR_W5B;
    if (idx < PR_COPY4) { ((float4*)out)[idx] = ((const float4*)answer)[idx]; }
}

// E_i[n][j] = sum_k enc[n][k]*W0[i*128+k][j]. Grid 196x4 = 784 blocks.
__global__ __launch_bounds__(512) void prep_e_kernel(
    const float* __restrict__ encoded, const bf16* __restrict__ W0sw,
    bf16* __restrict__ E)
{
    __shared__ bf16 sA[128][136];
    __shared__ bf16 sT[128][40];
    const int tid = threadIdx.x;
    const int row0 = (blockIdx.x >> 2) * 128;
    const int ntb  = blockIdx.x & 3;
    for (int c = tid; c < 4096; c += 512) {      // 128 rows x 32 float4
        int row = c >> 5, seg = c & 31;
        int rr = row0 + row; if (rr >= NN) rr = NN - 1;
        float4 v = *(const float4*)(encoded + (size_t)rr * 128 + seg * 4);
        bf16 pk[4] = {(bf16)v.x, (bf16)v.y, (bf16)v.z, (bf16)v.w};
        *(uint2*)(&sA[row][seg * 4]) = *(const uint2*)pk;
    }
    __syncthreads();
    const int wv = tid >> 6, lane = tid & 63;
    const int fr = lane & 15, quad = lane >> 4;
    const bf16* aBase = &sA[wv * 16 + fr][quad * 8];
    bf16x8 aFv[4];
    #pragma unroll
    for (int kcc = 0; kcc < 4; ++kcc) aFv[kcc] = *(const bf16x8*)(aBase + kcc * 32);
    const int orow = tid >> 2, oseg = tid & 3;
    #pragma unroll
    for (int i = 0; i < 4; ++i) {
        #pragma unroll
        for (int ntl = 0; ntl < 2; ++ntl) {
            int nt = ntb * 2 + ntl;
            f32x4 acc = {0.f, 0.f, 0.f, 0.f};
            #pragma unroll
            for (int kcc = 0; kcc < 4; ++kcc) {
                bf16x8 bF = *(const bf16x8*)(W0sw + ((size_t)nt * 16 + i * 4 + kcc) * 512 + lane * 8);
                acc = __builtin_amdgcn_mfma_f32_16x16x32_bf16(aFv[kcc], bF, acc, 0, 0, 0);
            }
            #pragma unroll
            for (int reg = 0; reg < 4; ++reg)
                sT[wv * 16 + quad * 4 + reg][ntl * 16 + fr] = (bf16)acc[reg];
        }
        __syncthreads();
        if (row0 + orow < NN)
            *(bf16x8*)(E + ((size_t)i * NN + row0 + orow) * 128 + ntb * 32 + oseg * 8) =
                *(const bf16x8*)(&sT[orow][oseg * 8]);
        __syncthreads();
    }
}

// ---------------------------------------------------------------------------
// Main kernel, R15: barrier-free wave-private restructure.
//
// Old structure: 8 waves lock-stepped through 6 __syncthreads at 2 blocks/CU
// (74 KB LDS) -> counters showed MfmaUtil 11 / VALUBusy 36 / Occ 40, i.e.
// stall-dominated, not pipe-bound. Observation: the work is already
// wave-aligned (wave wv owns propers wv*4..+3 = rows wv*16..+15). Each wave
// now computes the FULL N=128 of its own 16 rows (8 nt x 4 kc = 32 MFMAs per
// layer, same total MFMA count), its own geometry (lanes 0..15, one row each,
// sn/cs/dl broadcast via __shfl), and its own scatter. All cross-lane traffic
// is wave-private LDS, ordered by s_waitcnt lgkmcnt(0) fences (asm with
// "memory" clobber; consumers are DS ops so rule-18's MFMA-hoist hazard does
// not apply). Zero __syncthreads. One 16x136 bf16 buffer per wave, reused
// in-place across layers (all 4 A-frags register-read before any overwrite):
// LDS 74 KB -> ~38 KB -> 3-4 blocks/CU of mutually unsynchronized waves.
// ---------------------------------------------------------------------------
__global__ __launch_bounds__(512, 6) void main_kernel(
    const float* __restrict__ coords, const int* __restrict__ propers,
    const float* __restrict__ b1, const float* __restrict__ b2,
    const float* __restrict__ b3,
    const bf16* __restrict__ E, const bf16* __restrict__ W1sw,
    const bf16* __restrict__ W2sw, const bf16* __restrict__ W3sw,
    const bf16* __restrict__ WtB, const bf16* __restrict__ W5B,
    float* __restrict__ out)
{
    __shared__ __align__(16) bf16 sH[8][16][136];   // per-wave activation tile
    __shared__ float sScr[8][16][6];                // [0..2]=dh, [3..4]=delta
    __shared__ int   sNd[8][8];                     // per-wave {n0,n3} x 4 propers

    const int tid  = threadIdx.x;
    const int wv   = tid >> 6, lane = tid & 63;
    const int fr   = lane & 15, quad = lane >> 4;
    const int pw   = blockIdx.x * PB + wv * 4;      // first proper of this wave

#define LGKM0() asm volatile("s_waitcnt lgkmcnt(0)" ::: "memory")

    // ---- E gather: proper pw+quad, cols fr*8..fr*8+7 (same pattern as before) ----
    int4 pv = *(const int4*)(propers + (size_t)(pw + quad) * 4);
    bf16x8 e0 = *(const bf16x8*)(E + ((size_t)0 * NN + pv.x) * 128 + fr * 8);
    bf16x8 e1 = *(const bf16x8*)(E + ((size_t)1 * NN + pv.y) * 128 + fr * 8);
    bf16x8 e2 = *(const bf16x8*)(E + ((size_t)2 * NN + pv.z) * 128 + fr * 8);
    bf16x8 e3 = *(const bf16x8*)(E + ((size_t)3 * NN + pv.w) * 128 + fr * 8);
    if (fr == 0) { sNd[wv][quad * 2] = pv.x; sNd[wv][quad * 2 + 1] = pv.w; }
    bf16x8 w3v = *(const bf16x8*)(W5B + 0 * 128 + fr * 8);
    bf16x8 w4v = *(const bf16x8*)(W5B + 1 * 128 + fr * 8);
    bf16x8 w5v = *(const bf16x8*)(W5B + 2 * 128 + fr * 8);

    // ---- geometry: lanes 0..15 each own one of the wave's 16 rows ----
    // (same total coords-load count as before: 16 lanes x 8 waves = 128/block)
    float snl = 0.f, csl = 1.f, dll = 0.f;
    if (lane < 16) {
        int pp_ = lane >> 2, t = lane & 3;
        int4 pg = *(const int4*)(propers + (size_t)(pw + pp_) * 4);
        const float* c0 = coords + (size_t)pg.x * 12 + t * 3;
        const float* c1 = coords + (size_t)pg.y * 12 + t * 3;
        const float* c2 = coords + (size_t)pg.z * 12 + t * 3;
        const float* c3 = coords + (size_t)pg.w * 12 + t * 3;
        float u1x = c1[0]-c0[0], u1y = c1[1]-c0[1], u1z = c1[2]-c0[2];
        float u2x = c2[0]-c1[0], u2y = c2[1]-c1[1], u2z = c2[2]-c1[2];
        float u3x = c3[0]-c2[0], u3y = c3[1]-c2[1], u3z = c3[2]-c2[2];
        float ax = u1y*u2z - u1z*u2y, ay = u1z*u2x - u1x*u2z, az = u1x*u2y - u1y*u2x;
        float bx = u2y*u3z - u2z*u3y, by = u2z*u3x - u2x*u3z, bz = u2x*u3y - u2y*u3x;
        float u2n = sqrtf(u2x*u2x + u2y*u2y + u2z*u2z);
        float num = u2n * (u1x*bx + u1y*by + u1z*bz);
        float den = ax*bx + ay*by + az*bz;
        float hyp = sqrtf(num*num + den*den);
        if (hyp > 1e-30f) { float ih = 1.0f / hyp; snl = num * ih; csl = den * ih; }
        else { snl = 0.0f; csl = 1.0f; }
        float drx = c0[0]-c3[0], dry = c0[1]-c3[1], drz = c0[2]-c3[2];
        dll = sqrtf(fmaxf(drx*drx + dry*dry + drz*drz, 1e-12f));
        float il = 1.0f / dll;
        sScr[wv][lane][0] = drx * il;
        sScr[wv][lane][1] = dry * il;
        sScr[wv][lane][2] = drz * il;
    }

    // ---- h0 = leaky(g + Wt[t] + sn*w513 + cs*w514 + dl*w515) -> sH[wv] ----
    {
        float g[8], w3f[8], w4f[8], w5f[8];
        #pragma unroll
        for (int j = 0; j < 8; ++j) {
            g[j]   = (float)e0[j] + (float)e1[j] + (float)e2[j] + (float)e3[j];
            w3f[j] = (float)w3v[j]; w4f[j] = (float)w4v[j]; w5f[j] = (float)w5v[j];
        }
        #pragma unroll
        for (int t = 0; t < 4; ++t) {
            int r = quad * 4 + t;                         // wave-relative row
            bf16x8 wtv = *(const bf16x8*)(WtB + t * 128 + fr * 8);
            float sn = __shfl(snl, r), cs = __shfl(csl, r), dl = __shfl(dll, r);
            bf16 hv[8];
            #pragma unroll
            for (int j = 0; j < 8; ++j) {
                float v = g[j] + (float)wtv[j] + sn * w3f[j] + cs * w4f[j] + dl * w5f[j];
                v = fmaxf(v, LEAKY * v);
                hv[j] = (bf16)v;
            }
            *(bf16x8*)(&sH[wv][r][fr * 8]) = *(const bf16x8*)hv;
        }
    }

    // ---- dense layer template: read 4 A-frags (full K) into regs, fence,
    //      then 2 N-halves of {16 MFMA + epilogue} writing the SAME buffer ----
#define DENSE_LAYER(Wsw, bvec)                                                  \
    {                                                                           \
        LGKM0();   /* all prior ds_writes to sH[wv] drained before reads */     \
        bf16x8 aF[4];                                                           \
        const bf16* aRow = &sH[wv][fr][quad * 8];                               \
        _Pragma("unroll")                                                       \
        for (int kc = 0; kc < 4; ++kc)                                          \
            aF[kc] = *(const bf16x8*)(aRow + kc * 32);                          \
        LGKM0();   /* reads landed in regs before in-place overwrite below */   \
        _Pragma("unroll")                                                       \
        for (int hh = 0; hh < 2; ++hh) {                                        \
            f32x4 acc[4];                                                       \
            _Pragma("unroll")                                                   \
            for (int nt = 0; nt < 4; ++nt) acc[nt] = (f32x4){0.f,0.f,0.f,0.f};  \
            _Pragma("unroll")                                                   \
            for (int kc = 0; kc < 4; ++kc) {                                    \
                _Pragma("unroll")                                               \
                for (int nt = 0; nt < 4; ++nt) {                                \
                    bf16x8 bF = *(const bf16x8*)(Wsw +                          \
                        ((size_t)((hh * 4 + nt) * 4 + kc)) * 512 + lane * 8);   \
                    acc[nt] = __builtin_amdgcn_mfma_f32_16x16x32_bf16(          \
                        aF[kc], bF, acc[nt], 0, 0, 0);                          \
                }                                                               \
            }                                                                   \
            _Pragma("unroll")                                                   \
            for (int nt = 0; nt < 4; ++nt) {                                    \
                int j = (hh * 4 + nt) * 16 + fr;                                \
                float bb = bvec[j];                                             \
                _Pragma("unroll")                                               \
                for (int reg = 0; reg < 4; ++reg) {                             \
                    float v = acc[nt][reg] + bb;                                \
                    v = fmaxf(v, LEAKY * v);                                    \
                    sH[wv][quad * 4 + reg][j] = (bf16)v;                        \
                }                                                               \
            }                                                                   \
        }                                                                       \
    }

    DENSE_LAYER(W1sw, b1)      // h1 = leaky(h0 @ W1 + b1), in place
    DENSE_LAYER(W2sw, b2)      // h2 = leaky(h1 @ W2 + b2), in place

    // ---- delta = h2 @ W3 + b3 (zero-padded to 16 cols) ----
    {
        LGKM0();
        bf16x8 aF[4];
        const bf16* aRow = &sH[wv][fr][quad * 8];
        #pragma unroll
        for (int kc = 0; kc < 4; ++kc)
            aF[kc] = *(const bf16x8*)(aRow + kc * 32);
        f32x4 dacc = {0.f, 0.f, 0.f, 0.f};
        #pragma unroll
        for (int kc = 0; kc < 4; ++kc) {
            bf16x8 bF = *(const bf16x8*)(W3sw + (size_t)kc * 512 + lane * 8);
            dacc = __builtin_amdgcn_mfma_f32_16x16x32_bf16(aF[kc], bF, dacc, 0, 0, 0);
        }
        if (fr < 2) {
            float bb = b3[fr];
            #pragma unroll
            for (int reg = 0; reg < 4; ++reg)
                sScr[wv][quad * 4 + reg][3 + fr] = dacc[reg] + bb;
        }
    }

    // ---- scatter-add: per wave 16 rows x 6 atomics = 96 items over 64 lanes ----
    LGKM0();   // delta + dh + sNd visible to all lanes of this wave
    for (int idx = lane; idx < 96; idx += 64) {
        int r = idx / 6, c = idx - (idx / 6) * 6;
        int side = c / 3, ax = c - side * 3;
        int node = sNd[wv][(r >> 2) * 2 + side];
        float dval = (side ? 0.5f : -0.5f) * sScr[wv][r][3 + side];
        atomicAdd(out + (size_t)node * 12 + (r & 3) * 3 + ax, dval * sScr[wv][r][ax]);
    }
#undef DENSE_LAYER
#undef LGKM0
}

extern "C" void kernel_launch(void* const* d_in, const int* in_sizes, int n_in,
                              void* d_out, int out_size, void* d_ws, size_t ws_size,
                              hipStream_t stream) {
    const float* coords  = (const float*)d_in[0];
    const int*   propers = (const int*)d_in[1];
    const float* encoded = (const float*)d_in[2];
    const float* tvec    = (const float*)d_in[3];
    const float* answer  = (const float*)d_in[4];
    const float* W0 = (const float*)d_in[5];
    const float* b0 = (const float*)d_in[6];
    const float* W1 = (const float*)d_in[7];
    const float* b1 = (const float*)d_in[8];
    const float* W2 = (const float*)d_in[9];
    const float* b2 = (const float*)d_in[10];
    const float* W3 = (const float*)d_in[11];
    const float* b3 = (const float*)d_in[12];
    float* out = (float*)d_out;
    char* ws = (char*)d_ws;
    bf16* W0sw = (bf16*)(ws + OFF_W0SW);
    bf16* W1sw = (bf16*)(ws + OFF_W1SW);
    bf16* W2sw = (bf16*)(ws + OFF_W2SW);
    bf16* W3sw = (bf16*)(ws + OFF_W3SW);
    bf16* WtB  = (bf16*)(ws + OFF_WTB);
    bf16* W5B  = (bf16*)(ws + OFF_W5B);
    bf16* E    = (bf16*)(ws + OFF_E);

    int prep_blocks = (PR_TOTAL + 255) / 256;
    prep_kernel<<<prep_blocks, 256, 0, stream>>>(W0, W1, W2, W3, answer, tvec, b0,
                                                 W0sw, W1sw, W2sw, W3sw, WtB, W5B, out);
    prep_e_kernel<<<196 * 4, 512, 0, stream>>>(encoded, W0sw, E);
    main_kernel<<<PP / PB, 512, 0, stream>>>(coords, propers, b1, b2, b3,
                                             E, W1sw, W2sw, W3sw, WtB, W5B, out);
}

// Round 2
// 169.719 us; speedup vs baseline: 1.1938x; 1.1938x over previous
//
#include <hip/hip_runtime.h>
#include <hip/hip_bf16.h>

// ---- problem constants ----
#define NN 25000
#define PP 100000
#define TT 4
#define DD 128
#define LEAKY 0.001f

#define PB 32          // propers per block (8 waves x 4 propers)
#define ROWS 128       // PB * TT rows of the MLP per block

typedef __bf16 bf16;
typedef __bf16 bf16x8 __attribute__((ext_vector_type(8)));
typedef float  f32x4  __attribute__((ext_vector_type(4)));

// ---- workspace layout (bytes) ----
#define OFF_W0SW  0u                    // 128 chunks * 1KB (fragment order)
#define OFF_W1SW  131072u               // 32 chunks * 1KB
#define OFF_W2SW  163840u               // 32 chunks * 1KB
#define OFF_W3SW  196608u               // 4 chunks * 1KB
#define OFF_WTB   200704u               // Wt[t][j] = t*W0[512]+b0, 4*128 bf16
#define OFF_W5B   201728u               // W0 rows 513..515 as bf16
#define OFF_E     202496u               // 4 tables [NN][128] bf16 = 25,600,000 B
#define WS_END    25802496u

// prep work partition (thread counts)
#define PR_W0SW  65536
#define PR_W1SW  16384
#define PR_W2SW  16384
#define PR_W3SW  2048
#define PR_WTB   512
#define PR_W5B   384
#define PR_COPY4 75000
#define PR_TOTAL (PR_W0SW + PR_W1SW + PR_W2SW + PR_W3SW + PR_WTB + PR_W5B + PR_COPY4)

#define LGKM0() asm volatile("s_waitcnt lgkmcnt(0)" ::: "memory")

__device__ __forceinline__ void gload_lds16(const void* g, void* l) {
    __builtin_amdgcn_global_load_lds(
        (const __attribute__((address_space(1))) void*)g,
        (__attribute__((address_space(3))) void*)l, 16, 0, 0);
}

__global__ __launch_bounds__(256) void prep_kernel(
    const float* __restrict__ W0, const float* __restrict__ W1,
    const float* __restrict__ W2, const float* __restrict__ W3,
    const float* __restrict__ answer, const float* __restrict__ tvec,
    const float* __restrict__ b0,
    bf16* __restrict__ W0sw, bf16* __restrict__ W1sw, bf16* __restrict__ W2sw,
    bf16* __restrict__ W3sw, bf16* __restrict__ WtB, bf16* __restrict__ W5B,
    float* __restrict__ out)
{
    int idx = blockIdx.x * 256 + threadIdx.x;
    if (idx < PR_W0SW) {
        int j = idx & 7, lane = (idx >> 3) & 63, c = idx >> 9;
        int fr = lane & 15, quad = lane >> 4;
        int kc = c & 15, iwv = c >> 4;
        int k = kc * 32 + quad * 8 + j;
        W0sw[idx] = (bf16)W0[k * 128 + iwv * 16 + fr];
        return;
    }
    idx -= PR_W0SW;
    if (idx < PR_W1SW) {
        int j = idx & 7, lane = (idx >> 3) & 63, c = idx >> 9;
        int fr = lane & 15, quad = lane >> 4;
        int kc = c & 3, nt = c >> 2;
        int k = kc * 32 + quad * 8 + j;
        W1sw[idx] = (bf16)W1[k * 128 + nt * 16 + fr];
        return;
    }
    idx -= PR_W1SW;
    if (idx < PR_W2SW) {
        int j = idx & 7, lane = (idx >> 3) & 63, c = idx >> 9;
        int fr = lane & 15, quad = lane >> 4;
        int kc = c & 3, nt = c >> 2;
        int k = kc * 32 + quad * 8 + j;
        W2sw[idx] = (bf16)W2[k * 128 + nt * 16 + fr];
        return;
    }
    idx -= PR_W2SW;
    if (idx < PR_W3SW) {
        int j = idx & 7, lane = (idx >> 3) & 63, kc = idx >> 9;
        int fr = lane & 15, quad = lane >> 4;
        int k = kc * 32 + quad * 8 + j;
        W3sw[idx] = (fr < 2) ? (bf16)W3[k * 2 + fr] : (bf16)0.0f;
        return;
    }
    idx -= PR_W3SW;
    if (idx < PR_WTB) {                 // Wt[t][j] = tvec[t]*W0[512][j] + b0[j]
        int t = idx >> 7, j = idx & 127;
        WtB[idx] = (bf16)(tvec[t] * W0[512 * 128 + j] + b0[j]);
        return;
    }
    idx -= PR_WTB;
    if (idx < PR_W5B) {                 // W0 rows 513,514,515 -> bf16
        W5B[idx] = (bf16)W0[(513 + (idx >> 7)) * 128 + (idx & 127)];
        return;
    }
    idx -= PR_W5B;
    if (idx < PR_COPY4) { ((float4*)out)[idx] = ((const float4*)answer)[idx]; }
}

// E_i[n][j] = sum_k enc[n][k]*W0[i*128+k][j]. Grid 196x4 = 784 blocks.
// R16: the per-i __syncthreads pairs are replaced by wave-local lgkm fences —
// sT is wave-private on BOTH sides (writes rows wv*16+quad*4+reg, reads rows
// tid>>2 in [wv*16, wv*16+16)), so block-wide sync was pure overhead.
__global__ __launch_bounds__(512) void prep_e_kernel(
    const float* __restrict__ encoded, const bf16* __restrict__ W0sw,
    bf16* __restrict__ E)
{
    __shared__ bf16 sA[128][136];
    __shared__ bf16 sT[128][40];
    const int tid = threadIdx.x;
    const int row0 = (blockIdx.x >> 2) * 128;
    const int ntb  = blockIdx.x & 3;
    for (int c = tid; c < 4096; c += 512) {      // 128 rows x 32 float4
        int row = c >> 5, seg = c & 31;
        int rr = row0 + row; if (rr >= NN) rr = NN - 1;
        float4 v = *(const float4*)(encoded + (size_t)rr * 128 + seg * 4);
        bf16 pk[4] = {(bf16)v.x, (bf16)v.y, (bf16)v.z, (bf16)v.w};
        *(uint2*)(&sA[row][seg * 4]) = *(const uint2*)pk;
    }
    __syncthreads();                             // sA staged (cross-wave) — only barrier
    const int wv = tid >> 6, lane = tid & 63;
    const int fr = lane & 15, quad = lane >> 4;
    const bf16* aBase = &sA[wv * 16 + fr][quad * 8];
    bf16x8 aFv[4];
    #pragma unroll
    for (int kcc = 0; kcc < 4; ++kcc) aFv[kcc] = *(const bf16x8*)(aBase + kcc * 32);
    const int orow = tid >> 2, oseg = tid & 3;
    #pragma unroll
    for (int i = 0; i < 4; ++i) {
        #pragma unroll
        for (int ntl = 0; ntl < 2; ++ntl) {
            int nt = ntb * 2 + ntl;
            f32x4 acc = {0.f, 0.f, 0.f, 0.f};
            #pragma unroll
            for (int kcc = 0; kcc < 4; ++kcc) {
                bf16x8 bF = *(const bf16x8*)(W0sw + ((size_t)nt * 16 + i * 4 + kcc) * 512 + lane * 8);
                acc = __builtin_amdgcn_mfma_f32_16x16x32_bf16(aFv[kcc], bF, acc, 0, 0, 0);
            }
            #pragma unroll
            for (int reg = 0; reg < 4; ++reg)
                sT[wv * 16 + quad * 4 + reg][ntl * 16 + fr] = (bf16)acc[reg];
        }
        LGKM0();                                 // own sT writes visible to own wave
        bf16x8 ev = *(const bf16x8*)(&sT[orow][oseg * 8]);
        LGKM0();                                 // reads retired before next i's overwrite
        if (row0 + orow < NN)
            *(bf16x8*)(E + ((size_t)i * NN + row0 + orow) * 128 + ntb * 32 + oseg * 8) = ev;
    }
}

// ---------------------------------------------------------------------------
// Main kernel, R16: block-shared weights in LDS.
//
// R15 post-mortem: removing all barriers and raising occupancy 40->59% changed
// nothing (100->105 us) — the wall is bandwidth, not latency/sync. Each wave
// streamed the ENTIRE W1+W2+W3 set from global: 68 KB/wave x 25k waves =
// 1.7 GB of L2 reads (~16 TB/s sustained, ~50% of chip L2 ceiling and ~49 us
// of per-XCD L2 occupancy) on top of the 102 MB E-gather and 2.4 M atomics.
// Fix: stage W1(+W3) then W2 into a 36 KB LDS buffer once per block — 8 waves
// share it -> weight L2 traffic drops 8x to ~213 MB; bF reads become
// contiguous conflict-free ds_read_b128 against CU-private LDS bandwidth.
// Costs 3 __syncthreads and 75 KB LDS (2 blocks/CU, 16 waves) — acceptable
// since R15 proved occupancy isn't the lever. Biases preloaded to registers
// (removes 16 late scalar global loads per wave). sH stays wave-private with
// lgkm fences; wave still owns 1 M-tile x full N=128.
// ---------------------------------------------------------------------------
__global__ __launch_bounds__(512, 4) void main_kernel(
    const float* __restrict__ coords, const int* __restrict__ propers,
    const float* __restrict__ b1, const float* __restrict__ b2,
    const float* __restrict__ b3,
    const bf16* __restrict__ E, const bf16* __restrict__ W1sw,
    const bf16* __restrict__ W2sw, const bf16* __restrict__ W3sw,
    const bf16* __restrict__ WtB, const bf16* __restrict__ W5B,
    float* __restrict__ out)
{
    __shared__ __align__(16) bf16 sH[8][16][136];   // per-wave activation tile
    __shared__ __align__(16) bf16 sW[18432];        // 32KB W1/W2 + 4KB W3 frags
    __shared__ float sScr[8][16][6];                // [0..2]=dh, [3..4]=delta
    __shared__ int   sNd[8][8];                     // per-wave {n0,n3} x 4 propers

    const int tid  = threadIdx.x;
    const int wv   = tid >> 6, lane = tid & 63;
    const int fr   = lane & 15, quad = lane >> 4;
    const int pw   = blockIdx.x * PB + wv * 4;      // first proper of this wave

    // ---- stage W1 (32KB) + W3 (4KB) into LDS, async (drained at B1) ----
    {
        const char* g1 = (const char*)W1sw;
        char* l = (char*)&sW[0];
        #pragma unroll
        for (int r2 = 0; r2 < 4; ++r2)
            gload_lds16(g1 + r2 * 8192 + wv * 1024 + lane * 16,
                        l + r2 * 8192 + wv * 1024);
        if (wv < 4)
            gload_lds16((const char*)W3sw + wv * 1024 + lane * 16,
                        l + 32768 + wv * 1024);
    }

    // ---- E gather: proper pw+quad, cols fr*8..fr*8+7 ----
    int4 pv = *(const int4*)(propers + (size_t)(pw + quad) * 4);
    bf16x8 e0 = *(const bf16x8*)(E + ((size_t)0 * NN + pv.x) * 128 + fr * 8);
    bf16x8 e1 = *(const bf16x8*)(E + ((size_t)1 * NN + pv.y) * 128 + fr * 8);
    bf16x8 e2 = *(const bf16x8*)(E + ((size_t)2 * NN + pv.z) * 128 + fr * 8);
    bf16x8 e3 = *(const bf16x8*)(E + ((size_t)3 * NN + pv.w) * 128 + fr * 8);
    if (fr == 0) { sNd[wv][quad * 2] = pv.x; sNd[wv][quad * 2 + 1] = pv.w; }
    bf16x8 w3v = *(const bf16x8*)(W5B + 0 * 128 + fr * 8);
    bf16x8 w4v = *(const bf16x8*)(W5B + 1 * 128 + fr * 8);
    bf16x8 w5v = *(const bf16x8*)(W5B + 2 * 128 + fr * 8);

    // ---- bias preload (overlaps gather latency; kills late scalar loads) ----
    float b1r[8], b2r[8];
    #pragma unroll
    for (int i = 0; i < 8; ++i) {
        b1r[i] = b1[i * 16 + fr];
        b2r[i] = b2[i * 16 + fr];
    }
    float b3r = (fr < 2) ? b3[fr] : 0.0f;

    // ---- geometry: lanes 0..15 each own one of the wave's 16 rows ----
    float snl = 0.f, csl = 1.f, dll = 0.f;
    if (lane < 16) {
        int pp_ = lane >> 2, t = lane & 3;
        int4 pg = *(const int4*)(propers + (size_t)(pw + pp_) * 4);
        const float* c0 = coords + (size_t)pg.x * 12 + t * 3;
        const float* c1 = coords + (size_t)pg.y * 12 + t * 3;
        const float* c2 = coords + (size_t)pg.z * 12 + t * 3;
        const float* c3 = coords + (size_t)pg.w * 12 + t * 3;
        float u1x = c1[0]-c0[0], u1y = c1[1]-c0[1], u1z = c1[2]-c0[2];
        float u2x = c2[0]-c1[0], u2y = c2[1]-c1[1], u2z = c2[2]-c1[2];
        float u3x = c3[0]-c2[0], u3y = c3[1]-c2[1], u3z = c3[2]-c2[2];
        float ax = u1y*u2z - u1z*u2y, ay = u1z*u2x - u1x*u2z, az = u1x*u2y - u1y*u2x;
        float bx = u2y*u3z - u2z*u3y, by = u2z*u3x - u2x*u3z, bz = u2x*u3y - u2y*u3x;
        float u2n = sqrtf(u2x*u2x + u2y*u2y + u2z*u2z);
        float num = u2n * (u1x*bx + u1y*by + u1z*bz);
        float den = ax*bx + ay*by + az*bz;
        float hyp = sqrtf(num*num + den*den);
        if (hyp > 1e-30f) { float ih = 1.0f / hyp; snl = num * ih; csl = den * ih; }
        else { snl = 0.0f; csl = 1.0f; }
        float drx = c0[0]-c3[0], dry = c0[1]-c3[1], drz = c0[2]-c3[2];
        dll = sqrtf(fmaxf(drx*drx + dry*dry + drz*drz, 1e-12f));
        float il = 1.0f / dll;
        sScr[wv][lane][0] = drx * il;
        sScr[wv][lane][1] = dry * il;
        sScr[wv][lane][2] = drz * il;
    }

    // ---- h0 = leaky(g + Wt[t] + sn*w513 + cs*w514 + dl*w515) -> sH[wv] ----
    {
        float g[8], w3f[8], w4f[8], w5f[8];
        #pragma unroll
        for (int j = 0; j < 8; ++j) {
            g[j]   = (float)e0[j] + (float)e1[j] + (float)e2[j] + (float)e3[j];
            w3f[j] = (float)w3v[j]; w4f[j] = (float)w4v[j]; w5f[j] = (float)w5v[j];
        }
        #pragma unroll
        for (int t = 0; t < 4; ++t) {
            int r = quad * 4 + t;                         // wave-relative row
            bf16x8 wtv = *(const bf16x8*)(WtB + t * 128 + fr * 8);
            float sn = __shfl(snl, r), cs = __shfl(csl, r), dl = __shfl(dll, r);
            bf16 hv[8];
            #pragma unroll
            for (int j = 0; j < 8; ++j) {
                float v = g[j] + (float)wtv[j] + sn * w3f[j] + cs * w4f[j] + dl * w5f[j];
                v = fmaxf(v, LEAKY * v);
                hv[j] = (bf16)v;
            }
            *(bf16x8*)(&sH[wv][r][fr * 8]) = *(const bf16x8*)hv;
        }
    }
    __syncthreads();   // B1: W1+W3 staged (vmcnt drained); h0 in sH is wave-local

    // ---- dense layer: A-frags from own sH, B-frags from block-shared LDS ----
#define DENSE_LAYER(BR)                                                         \
    {                                                                           \
        LGKM0();   /* prior ds_writes to sH[wv] drained before reads */         \
        bf16x8 aF[4];                                                           \
        const bf16* aRow = &sH[wv][fr][quad * 8];                               \
        _Pragma("unroll")                                                       \
        for (int kc = 0; kc < 4; ++kc)                                          \
            aF[kc] = *(const bf16x8*)(aRow + kc * 32);                          \
        LGKM0();   /* reads landed in regs before in-place overwrite below */   \
        _Pragma("unroll")                                                       \
        for (int hh = 0; hh < 2; ++hh) {                                        \
            f32x4 acc[4];                                                       \
            _Pragma("unroll")                                                   \
            for (int nt = 0; nt < 4; ++nt) acc[nt] = (f32x4){0.f,0.f,0.f,0.f};  \
            _Pragma("unroll")                                                   \
            for (int kc = 0; kc < 4; ++kc) {                                    \
                _Pragma("unroll")                                               \
                for (int nt = 0; nt < 4; ++nt) {                                \
                    bf16x8 bF = *(const bf16x8*)(sW +                           \
                        ((hh * 4 + nt) * 4 + kc) * 512 + lane * 8);             \
                    acc[nt] = __builtin_amdgcn_mfma_f32_16x16x32_bf16(          \
                        aF[kc], bF, acc[nt], 0, 0, 0);                          \
                }                                                               \
            }                                                                   \
            _Pragma("unroll")                                                   \
            for (int nt = 0; nt < 4; ++nt) {                                    \
                int j = (hh * 4 + nt) * 16 + fr;                                \
                float bb = BR[hh * 4 + nt];                                     \
                _Pragma("unroll")                                               \
                for (int reg = 0; reg < 4; ++reg) {                             \
                    float v = acc[nt][reg] + bb;                                \
                    v = fmaxf(v, LEAKY * v);                                    \
                    sH[wv][quad * 4 + reg][j] = (bf16)v;                        \
                }                                                               \
            }                                                                   \
        }                                                                       \
    }

    DENSE_LAYER(b1r)           // h1 = leaky(h0 @ W1 + b1), in place
    __syncthreads();           // B2: all waves done reading W1 frags
    {                          // stage W2 over W1 (async, drained at B3)
        const char* g2 = (const char*)W2sw;
        char* l = (char*)&sW[0];
        #pragma unroll
        for (int r2 = 0; r2 < 4; ++r2)
            gload_lds16(g2 + r2 * 8192 + wv * 1024 + lane * 16,
                        l + r2 * 8192 + wv * 1024);
    }
    __syncthreads();           // B3: W2 staged
    DENSE_LAYER(b2r)           // h2 = leaky(h1 @ W2 + b2), in place

    // ---- delta = h2 @ W3 + b3 (zero-padded to 16 cols); W3 frags at sW+16384 ----
    {
        LGKM0();
        bf16x8 aF[4];
        const bf16* aRow = &sH[wv][fr][quad * 8];
        #pragma unroll
        for (int kc = 0; kc < 4; ++kc)
            aF[kc] = *(const bf16x8*)(aRow + kc * 32);
        f32x4 dacc = {0.f, 0.f, 0.f, 0.f};
        #pragma unroll
        for (int kc = 0; kc < 4; ++kc) {
            bf16x8 bF = *(const bf16x8*)(sW + 16384 + kc * 512 + lane * 8);
            dacc = __builtin_amdgcn_mfma_f32_16x16x32_bf16(aF[kc], bF, dacc, 0, 0, 0);
        }
        if (fr < 2) {
            #pragma unroll
            for (int reg = 0; reg < 4; ++reg)
                sScr[wv][quad * 4 + reg][3 + fr] = dacc[reg] + b3r;
        }
    }

    // ---- scatter-add: per wave 16 rows x 6 atomics = 96 items over 64 lanes ----
    LGKM0();   // delta + dh + sNd visible to all lanes of this wave
    for (int idx = lane; idx < 96; idx += 64) {
        int r = idx / 6, c = idx - (idx / 6) * 6;
        int side = c / 3, ax = c - side * 3;
        int node = sNd[wv][(r >> 2) * 2 + side];
        float dval = (side ? 0.5f : -0.5f) * sScr[wv][r][3 + side];
        atomicAdd(out + (size_t)node * 12 + (r & 3) * 3 + ax, dval * sScr[wv][r][ax]);
    }
#undef DENSE_LAYER
}

extern "C" void kernel_launch(void* const* d_in, const int* in_sizes, int n_in,
                              void* d_out, int out_size, void* d_ws, size_t ws_size,
                              hipStream_t stream) {
    const float* coords  = (const float*)d_in[0];
    const int*   propers = (const int*)d_in[1];
    const float* encoded = (const float*)d_in[2];
    const float* tvec    = (const float*)d_in[3];
    const float* answer  = (const float*)d_in[4];
    const float* W0 = (const float*)d_in[5];
    const float* b0 = (const float*)d_in[6];
    const float* W1 = (const float*)d_in[7];
    const float* b1 = (const float*)d_in[8];
    const float* W2 = (const float*)d_in[9];
    const float* b2 = (const float*)d_in[10];
    const float* W3 = (const float*)d_in[11];
    const float* b3 = (const float*)d_in[12];
    float* out = (float*)d_out;
    char* ws = (char*)d_ws;
    bf16* W0sw = (bf16*)(ws + OFF_W0SW);
    bf16* W1sw = (bf16*)(ws + OFF_W1SW);
    bf16* W2sw = (bf16*)(ws + OFF_W2SW);
    bf16* W3sw = (bf16*)(ws + OFF_W3SW);
    bf16* WtB  = (bf16*)(ws + OFF_WTB);
    bf16* W5B  = (bf16*)(ws + OFF_W5B);
    bf16* E    = (bf16*)(ws + OFF_E);

    int prep_blocks = (PR_TOTAL + 255) / 256;
    prep_kernel<<<prep_blocks, 256, 0, stream>>>(W0, W1, W2, W3, answer, tvec, b0,
                                                 W0sw, W1sw, W2sw, W3sw, WtB, W5B, out);
    prep_e_kernel<<<196 * 4, 512, 0, stream>>>(encoded, W0sw, E);
    main_kernel<<<PP / PB, 512, 0, stream>>>(coords, propers, b1, b2, b3,
                                             E, W1sw, W2sw, W3sw, WtB, W5B, out);
}

// Round 3
// 166.960 us; speedup vs baseline: 1.2136x; 1.0165x over previous
//
#include <hip/hip_runtime.h>
#include <hip/hip_bf16.h>

// ---- problem constants ----
#define NN 25000
#define PP 100000
#define TT 4
#define DD 128
#define LEAKY 0.001f

#define PB 32          // propers per block (8 waves x 4 propers)
#define ROWS 128       // PB * TT rows of the MLP per block

typedef __bf16 bf16;
typedef __bf16 bf16x8 __attribute__((ext_vector_type(8)));
typedef float  f32x4  __attribute__((ext_vector_type(4)));

// ---- workspace layout (bytes) ----
#define OFF_W0SW  0u                    // 128 chunks * 1KB (fragment order)
#define OFF_W1SW  131072u               // 32 chunks * 1KB
#define OFF_W2SW  163840u               // 32 chunks * 1KB
#define OFF_W3SW  196608u               // 4 chunks * 1KB
#define OFF_WTB   200704u               // Wt[t][j] = t*W0[512]+b0, 4*128 bf16
#define OFF_W5B   201728u               // W0 rows 513..515 as bf16
#define OFF_E     202496u               // 4 tables [NN][128] bf16 = 25,600,000 B
#define WS_END    25802496u

// prep work partition (thread counts) — R17: conversion sections vectorized
// 8 outputs/thread (bf16x8 stores), thread counts /8.
#define PR_W0SW  8192
#define PR_W1SW  2048
#define PR_W2SW  2048
#define PR_W3SW  256
#define PR_WTB   64
#define PR_W5B   48
#define PR_COPY4 75000
#define PR_TOTAL (PR_W0SW + PR_W1SW + PR_W2SW + PR_W3SW + PR_WTB + PR_W5B + PR_COPY4)

#define LGKM0() asm volatile("s_waitcnt lgkmcnt(0)" ::: "memory")

__device__ __forceinline__ void gload_lds16(const void* g, void* l) {
    __builtin_amdgcn_global_load_lds(
        (const __attribute__((address_space(1))) void*)g,
        (__attribute__((address_space(3))) void*)l, 16, 0, 0);
}

__global__ __launch_bounds__(256) void prep_kernel(
    const float* __restrict__ W0, const float* __restrict__ W1,
    const float* __restrict__ W2, const float* __restrict__ W3,
    const float* __restrict__ answer, const float* __restrict__ tvec,
    const float* __restrict__ b0,
    bf16* __restrict__ W0sw, bf16* __restrict__ W1sw, bf16* __restrict__ W2sw,
    bf16* __restrict__ W3sw, bf16* __restrict__ WtB, bf16* __restrict__ W5B,
    float* __restrict__ out)
{
    int idx = blockIdx.x * 256 + threadIdx.x;
    if (idx < PR_W0SW) {                 // one chunk-lane per thread: 8 elems
        int lane = idx & 63, c = idx >> 6;
        int fr = lane & 15, quad = lane >> 4;
        int kc = c & 15, iwv = c >> 4;
        bf16 v[8];
        #pragma unroll
        for (int j = 0; j < 8; ++j)
            v[j] = (bf16)W0[(kc * 32 + quad * 8 + j) * 128 + iwv * 16 + fr];
        *(bf16x8*)(W0sw + c * 512 + lane * 8) = *(const bf16x8*)v;
        return;
    }
    idx -= PR_W0SW;
    if (idx < PR_W1SW) {
        int lane = idx & 63, c = idx >> 6;
        int fr = lane & 15, quad = lane >> 4;
        int kc = c & 3, nt = c >> 2;
        bf16 v[8];
        #pragma unroll
        for (int j = 0; j < 8; ++j)
            v[j] = (bf16)W1[(kc * 32 + quad * 8 + j) * 128 + nt * 16 + fr];
        *(bf16x8*)(W1sw + c * 512 + lane * 8) = *(const bf16x8*)v;
        return;
    }
    idx -= PR_W1SW;
    if (idx < PR_W2SW) {
        int lane = idx & 63, c = idx >> 6;
        int fr = lane & 15, quad = lane >> 4;
        int kc = c & 3, nt = c >> 2;
        bf16 v[8];
        #pragma unroll
        for (int j = 0; j < 8; ++j)
            v[j] = (bf16)W2[(kc * 32 + quad * 8 + j) * 128 + nt * 16 + fr];
        *(bf16x8*)(W2sw + c * 512 + lane * 8) = *(const bf16x8*)v;
        return;
    }
    idx -= PR_W2SW;
    if (idx < PR_W3SW) {
        int lane = idx & 63, kc = idx >> 6;
        int fr = lane & 15, quad = lane >> 4;
        bf16 v[8];
        #pragma unroll
        for (int j = 0; j < 8; ++j)
            v[j] = (fr < 2) ? (bf16)W3[(kc * 32 + quad * 8 + j) * 2 + fr] : (bf16)0.0f;
        *(bf16x8*)(W3sw + kc * 512 + lane * 8) = *(const bf16x8*)v;
        return;
    }
    idx -= PR_W3SW;
    if (idx < PR_WTB) {                 // Wt[t][j] = tvec[t]*W0[512][j] + b0[j]
        int t = idx >> 4, s = idx & 15;
        float tv = tvec[t];
        bf16 v[8];
        #pragma unroll
        for (int j = 0; j < 8; ++j)
            v[j] = (bf16)(tv * W0[512 * 128 + s * 8 + j] + b0[s * 8 + j]);
        *(bf16x8*)(WtB + t * 128 + s * 8) = *(const bf16x8*)v;
        return;
    }
    idx -= PR_WTB;
    if (idx < PR_W5B) {                 // W0 rows 513,514,515 -> bf16
        int r = idx >> 4, s = idx & 15;
        bf16 v[8];
        #pragma unroll
        for (int j = 0; j < 8; ++j)
            v[j] = (bf16)W0[(513 + r) * 128 + s * 8 + j];
        *(bf16x8*)(W5B + r * 128 + s * 8) = *(const bf16x8*)v;
        return;
    }
    idx -= PR_W5B;
    if (idx < PR_COPY4) { ((float4*)out)[idx] = ((const float4*)answer)[idx]; }
}

// E_i[n][j] = sum_k enc[n][k]*W0[i*128+k][j].
// R17: prep stack is ~96 us of the 169.7 total (constant across R0-R2 while
// main moved 100->105->74) and this kernel's work is only ~3.3 GFLOP /
// ~100 MB — it must be latency-bound at low occupancy (784 blocks, 45 KB
// LDS, ~12 waves/CU, long fenced serial chain per block). Same verified
// inner structure, re-tiled: 256-thread blocks on 64 rows -> 1564 blocks,
// 22.5 KB LDS (~7 blocks/CU, ~28 waves/CU latency hiding).
__global__ __launch_bounds__(256) void prep_e_kernel(
    const float* __restrict__ encoded, const bf16* __restrict__ W0sw,
    bf16* __restrict__ E)
{
    __shared__ bf16 sA[64][136];
    __shared__ bf16 sT[64][40];
    const int tid = threadIdx.x;
    const int row0 = (blockIdx.x >> 2) * 64;
    const int ntb  = blockIdx.x & 3;
    for (int c = tid; c < 2048; c += 256) {      // 64 rows x 32 float4
        int row = c >> 5, seg = c & 31;
        int rr = row0 + row; if (rr >= NN) rr = NN - 1;
        float4 v = *(const float4*)(encoded + (size_t)rr * 128 + seg * 4);
        bf16 pk[4] = {(bf16)v.x, (bf16)v.y, (bf16)v.z, (bf16)v.w};
        *(uint2*)(&sA[row][seg * 4]) = *(const uint2*)pk;
    }
    __syncthreads();                             // sA staged (cross-wave) — only barrier
    const int wv = tid >> 6, lane = tid & 63;
    const int fr = lane & 15, quad = lane >> 4;
    const bf16* aBase = &sA[wv * 16 + fr][quad * 8];
    bf16x8 aFv[4];
    #pragma unroll
    for (int kcc = 0; kcc < 4; ++kcc) aFv[kcc] = *(const bf16x8*)(aBase + kcc * 32);
    const int orow = tid >> 2, oseg = tid & 3;
    #pragma unroll
    for (int i = 0; i < 4; ++i) {
        #pragma unroll
        for (int ntl = 0; ntl < 2; ++ntl) {
            int nt = ntb * 2 + ntl;
            f32x4 acc = {0.f, 0.f, 0.f, 0.f};
            #pragma unroll
            for (int kcc = 0; kcc < 4; ++kcc) {
                bf16x8 bF = *(const bf16x8*)(W0sw + ((size_t)nt * 16 + i * 4 + kcc) * 512 + lane * 8);
                acc = __builtin_amdgcn_mfma_f32_16x16x32_bf16(aFv[kcc], bF, acc, 0, 0, 0);
            }
            #pragma unroll
            for (int reg = 0; reg < 4; ++reg)
                sT[wv * 16 + quad * 4 + reg][ntl * 16 + fr] = (bf16)acc[reg];
        }
        LGKM0();                                 // own sT writes visible to own wave
        bf16x8 ev = *(const bf16x8*)(&sT[orow][oseg * 8]);
        LGKM0();                                 // reads retired before next i's overwrite
        if (row0 + orow < NN)
            *(bf16x8*)(E + ((size_t)i * NN + row0 + orow) * 128 + ntb * 32 + oseg * 8) = ev;
    }
}

// ---------------------------------------------------------------------------
// Main kernel — UNCHANGED from R16 (74 us, verified). Block-shared weights in
// LDS (8x L2-traffic cut vs per-wave streaming), wave-private sH activation
// tiles with lgkm fences, biases preloaded to registers.
// ---------------------------------------------------------------------------
__global__ __launch_bounds__(512, 4) void main_kernel(
    const float* __restrict__ coords, const int* __restrict__ propers,
    const float* __restrict__ b1, const float* __restrict__ b2,
    const float* __restrict__ b3,
    const bf16* __restrict__ E, const bf16* __restrict__ W1sw,
    const bf16* __restrict__ W2sw, const bf16* __restrict__ W3sw,
    const bf16* __restrict__ WtB, const bf16* __restrict__ W5B,
    float* __restrict__ out)
{
    __shared__ __align__(16) bf16 sH[8][16][136];   // per-wave activation tile
    __shared__ __align__(16) bf16 sW[18432];        // 32KB W1/W2 + 4KB W3 frags
    __shared__ float sScr[8][16][6];                // [0..2]=dh, [3..4]=delta
    __shared__ int   sNd[8][8];                     // per-wave {n0,n3} x 4 propers

    const int tid  = threadIdx.x;
    const int wv   = tid >> 6, lane = tid & 63;
    const int fr   = lane & 15, quad = lane >> 4;
    const int pw   = blockIdx.x * PB + wv * 4;      // first proper of this wave

    // ---- stage W1 (32KB) + W3 (4KB) into LDS, async (drained at B1) ----
    {
        const char* g1 = (const char*)W1sw;
        char* l = (char*)&sW[0];
        #pragma unroll
        for (int r2 = 0; r2 < 4; ++r2)
            gload_lds16(g1 + r2 * 8192 + wv * 1024 + lane * 16,
                        l + r2 * 8192 + wv * 1024);
        if (wv < 4)
            gload_lds16((const char*)W3sw + wv * 1024 + lane * 16,
                        l + 32768 + wv * 1024);
    }

    // ---- E gather: proper pw+quad, cols fr*8..fr*8+7 ----
    int4 pv = *(const int4*)(propers + (size_t)(pw + quad) * 4);
    bf16x8 e0 = *(const bf16x8*)(E + ((size_t)0 * NN + pv.x) * 128 + fr * 8);
    bf16x8 e1 = *(const bf16x8*)(E + ((size_t)1 * NN + pv.y) * 128 + fr * 8);
    bf16x8 e2 = *(const bf16x8*)(E + ((size_t)2 * NN + pv.z) * 128 + fr * 8);
    bf16x8 e3 = *(const bf16x8*)(E + ((size_t)3 * NN + pv.w) * 128 + fr * 8);
    if (fr == 0) { sNd[wv][quad * 2] = pv.x; sNd[wv][quad * 2 + 1] = pv.w; }
    bf16x8 w3v = *(const bf16x8*)(W5B + 0 * 128 + fr * 8);
    bf16x8 w4v = *(const bf16x8*)(W5B + 1 * 128 + fr * 8);
    bf16x8 w5v = *(const bf16x8*)(W5B + 2 * 128 + fr * 8);

    // ---- bias preload (overlaps gather latency; kills late scalar loads) ----
    float b1r[8], b2r[8];
    #pragma unroll
    for (int i = 0; i < 8; ++i) {
        b1r[i] = b1[i * 16 + fr];
        b2r[i] = b2[i * 16 + fr];
    }
    float b3r = (fr < 2) ? b3[fr] : 0.0f;

    // ---- geometry: lanes 0..15 each own one of the wave's 16 rows ----
    float snl = 0.f, csl = 1.f, dll = 0.f;
    if (lane < 16) {
        int pp_ = lane >> 2, t = lane & 3;
        int4 pg = *(const int4*)(propers + (size_t)(pw + pp_) * 4);
        const float* c0 = coords + (size_t)pg.x * 12 + t * 3;
        const float* c1 = coords + (size_t)pg.y * 12 + t * 3;
        const float* c2 = coords + (size_t)pg.z * 12 + t * 3;
        const float* c3 = coords + (size_t)pg.w * 12 + t * 3;
        float u1x = c1[0]-c0[0], u1y = c1[1]-c0[1], u1z = c1[2]-c0[2];
        float u2x = c2[0]-c1[0], u2y = c2[1]-c1[1], u2z = c2[2]-c1[2];
        float u3x = c3[0]-c2[0], u3y = c3[1]-c2[1], u3z = c3[2]-c2[2];
        float ax = u1y*u2z - u1z*u2y, ay = u1z*u2x - u1x*u2z, az = u1x*u2y - u1y*u2x;
        float bx = u2y*u3z - u2z*u3y, by = u2z*u3x - u2x*u3z, bz = u2x*u3y - u2y*u3x;
        float u2n = sqrtf(u2x*u2x + u2y*u2y + u2z*u2z);
        float num = u2n * (u1x*bx + u1y*by + u1z*bz);
        float den = ax*bx + ay*by + az*bz;
        float hyp = sqrtf(num*num + den*den);
        if (hyp > 1e-30f) { float ih = 1.0f / hyp; snl = num * ih; csl = den * ih; }
        else { snl = 0.0f; csl = 1.0f; }
        float drx = c0[0]-c3[0], dry = c0[1]-c3[1], drz = c0[2]-c3[2];
        dll = sqrtf(fmaxf(drx*drx + dry*dry + drz*drz, 1e-12f));
        float il = 1.0f / dll;
        sScr[wv][lane][0] = drx * il;
        sScr[wv][lane][1] = dry * il;
        sScr[wv][lane][2] = drz * il;
    }

    // ---- h0 = leaky(g + Wt[t] + sn*w513 + cs*w514 + dl*w515) -> sH[wv] ----
    {
        float g[8], w3f[8], w4f[8], w5f[8];
        #pragma unroll
        for (int j = 0; j < 8; ++j) {
            g[j]   = (float)e0[j] + (float)e1[j] + (float)e2[j] + (float)e3[j];
            w3f[j] = (float)w3v[j]; w4f[j] = (float)w4v[j]; w5f[j] = (float)w5v[j];
        }
        #pragma unroll
        for (int t = 0; t < 4; ++t) {
            int r = quad * 4 + t;                         // wave-relative row
            bf16x8 wtv = *(const bf16x8*)(WtB + t * 128 + fr * 8);
            float sn = __shfl(snl, r), cs = __shfl(csl, r), dl = __shfl(dll, r);
            bf16 hv[8];
            #pragma unroll
            for (int j = 0; j < 8; ++j) {
                float v = g[j] + (float)wtv[j] + sn * w3f[j] + cs * w4f[j] + dl * w5f[j];
                v = fmaxf(v, LEAKY * v);
                hv[j] = (bf16)v;
            }
            *(bf16x8*)(&sH[wv][r][fr * 8]) = *(const bf16x8*)hv;
        }
    }
    __syncthreads();   // B1: W1+W3 staged (vmcnt drained); h0 in sH is wave-local

    // ---- dense layer: A-frags from own sH, B-frags from block-shared LDS ----
#define DENSE_LAYER(BR)                                                         \
    {                                                                           \
        LGKM0();   /* prior ds_writes to sH[wv] drained before reads */         \
        bf16x8 aF[4];                                                           \
        const bf16* aRow = &sH[wv][fr][quad * 8];                               \
        _Pragma("unroll")                                                       \
        for (int kc = 0; kc < 4; ++kc)                                          \
            aF[kc] = *(const bf16x8*)(aRow + kc * 32);                          \
        LGKM0();   /* reads landed in regs before in-place overwrite below */   \
        _Pragma("unroll")                                                       \
        for (int hh = 0; hh < 2; ++hh) {                                        \
            f32x4 acc[4];                                                       \
            _Pragma("unroll")                                                   \
            for (int nt = 0; nt < 4; ++nt) acc[nt] = (f32x4){0.f,0.f,0.f,0.f};  \
            _Pragma("unroll")                                                   \
            for (int kc = 0; kc < 4; ++kc) {                                    \
                _Pragma("unroll")                                               \
                for (int nt = 0; nt < 4; ++nt) {                                \
                    bf16x8 bF = *(const bf16x8*)(sW +                           \
                        ((hh * 4 + nt) * 4 + kc) * 512 + lane * 8);             \
                    acc[nt] = __builtin_amdgcn_mfma_f32_16x16x32_bf16(          \
                        aF[kc], bF, acc[nt], 0, 0, 0);                          \
                }                                                               \
            }                                                                   \
            _Pragma("unroll")                                                   \
            for (int nt = 0; nt < 4; ++nt) {                                    \
                int j = (hh * 4 + nt) * 16 + fr;                                \
                float bb = BR[hh * 4 + nt];                                     \
                _Pragma("unroll")                                               \
                for (int reg = 0; reg < 4; ++reg) {                             \
                    float v = acc[nt][reg] + bb;                                \
                    v = fmaxf(v, LEAKY * v);                                    \
                    sH[wv][quad * 4 + reg][j] = (bf16)v;                        \
                }                                                               \
            }                                                                   \
        }                                                                       \
    }

    DENSE_LAYER(b1r)           // h1 = leaky(h0 @ W1 + b1), in place
    __syncthreads();           // B2: all waves done reading W1 frags
    {                          // stage W2 over W1 (async, drained at B3)
        const char* g2 = (const char*)W2sw;
        char* l = (char*)&sW[0];
        #pragma unroll
        for (int r2 = 0; r2 < 4; ++r2)
            gload_lds16(g2 + r2 * 8192 + wv * 1024 + lane * 16,
                        l + r2 * 8192 + wv * 1024);
    }
    __syncthreads();           // B3: W2 staged
    DENSE_LAYER(b2r)           // h2 = leaky(h1 @ W2 + b2), in place

    // ---- delta = h2 @ W3 + b3 (zero-padded to 16 cols); W3 frags at sW+16384 ----
    {
        LGKM0();
        bf16x8 aF[4];
        const bf16* aRow = &sH[wv][fr][quad * 8];
        #pragma unroll
        for (int kc = 0; kc < 4; ++kc)
            aF[kc] = *(const bf16x8*)(aRow + kc * 32);
        f32x4 dacc = {0.f, 0.f, 0.f, 0.f};
        #pragma unroll
        for (int kc = 0; kc < 4; ++kc) {
            bf16x8 bF = *(const bf16x8*)(sW + 16384 + kc * 512 + lane * 8);
            dacc = __builtin_amdgcn_mfma_f32_16x16x32_bf16(aF[kc], bF, dacc, 0, 0, 0);
        }
        if (fr < 2) {
            #pragma unroll
            for (int reg = 0; reg < 4; ++reg)
                sScr[wv][quad * 4 + reg][3 + fr] = dacc[reg] + b3r;
        }
    }

    // ---- scatter-add: per wave 16 rows x 6 atomics = 96 items over 64 lanes ----
    LGKM0();   // delta + dh + sNd visible to all lanes of this wave
    for (int idx = lane; idx < 96; idx += 64) {
        int r = idx / 6, c = idx - (idx / 6) * 6;
        int side = c / 3, ax = c - side * 3;
        int node = sNd[wv][(r >> 2) * 2 + side];
        float dval = (side ? 0.5f : -0.5f) * sScr[wv][r][3 + side];
        atomicAdd(out + (size_t)node * 12 + (r & 3) * 3 + ax, dval * sScr[wv][r][ax]);
    }
#undef DENSE_LAYER
}

extern "C" void kernel_launch(void* const* d_in, const int* in_sizes, int n_in,
                              void* d_out, int out_size, void* d_ws, size_t ws_size,
                              hipStream_t stream) {
    const float* coords  = (const float*)d_in[0];
    const int*   propers = (const int*)d_in[1];
    const float* encoded = (const float*)d_in[2];
    const float* tvec    = (const float*)d_in[3];
    const float* answer  = (const float*)d_in[4];
    const float* W0 = (const float*)d_in[5];
    const float* b0 = (const float*)d_in[6];
    const float* W1 = (const float*)d_in[7];
    const float* b1 = (const float*)d_in[8];
    const float* W2 = (const float*)d_in[9];
    const float* b2 = (const float*)d_in[10];
    const float* W3 = (const float*)d_in[11];
    const float* b3 = (const float*)d_in[12];
    float* out = (float*)d_out;
    char* ws = (char*)d_ws;
    bf16* W0sw = (bf16*)(ws + OFF_W0SW);
    bf16* W1sw = (bf16*)(ws + OFF_W1SW);
    bf16* W2sw = (bf16*)(ws + OFF_W2SW);
    bf16* W3sw = (bf16*)(ws + OFF_W3SW);
    bf16* WtB  = (bf16*)(ws + OFF_WTB);
    bf16* W5B  = (bf16*)(ws + OFF_W5B);
    bf16* E    = (bf16*)(ws + OFF_E);

    int prep_blocks = (PR_TOTAL + 255) / 256;
    prep_kernel<<<prep_blocks, 256, 0, stream>>>(W0, W1, W2, W3, answer, tvec, b0,
                                                 W0sw, W1sw, W2sw, W3sw, WtB, W5B, out);
    prep_e_kernel<<<391 * 4, 256, 0, stream>>>(encoded, W0sw, E);
    main_kernel<<<PP / PB, 512, 0, stream>>>(coords, propers, b1, b2, b3,
                                             E, W1sw, W2sw, W3sw, WtB, W5B, out);
}

// Round 4
// 165.952 us; speedup vs baseline: 1.2209x; 1.0061x over previous
//
#include <hip/hip_runtime.h>
#include <hip/hip_bf16.h>

// ---- problem constants ----
#define NN 25000
#define PP 100000
#define TT 4
#define DD 128
#define LEAKY 0.001f

#define PB 32          // propers per block (8 waves x 4 propers)
#define ROWS 128       // PB * TT rows of the MLP per block

typedef __bf16 bf16;
typedef __bf16 bf16x8 __attribute__((ext_vector_type(8)));
typedef float  f32x4  __attribute__((ext_vector_type(4)));
typedef float  f32x2  __attribute__((ext_vector_type(2)));

// ---- workspace layout (bytes) ----
#define OFF_W0SW  0u                    // 128 chunks * 1KB (fragment order)
#define OFF_W1SW  131072u               // 32 chunks * 1KB
#define OFF_W2SW  163840u               // 32 chunks * 1KB
#define OFF_W3SW  196608u               // 4 chunks * 1KB
#define OFF_WTB   200704u               // Wt[t][j] = t*W0[512]+b0, 4*128 bf16
#define OFF_W5B   201728u               // W0 rows 513..515 as bf16
#define OFF_E     202496u               // 4 tables [NN][128] bf16 = 25,600,000 B
#define WS_END    25802496u

// prep work partition (thread counts) — conversion sections vectorized
// 8 outputs/thread (bf16x8 stores).
#define PR_W0SW  8192
#define PR_W1SW  2048
#define PR_W2SW  2048
#define PR_W3SW  256
#define PR_WTB   64
#define PR_W5B   48
#define PR_COPY4 75000
#define PR_TOTAL (PR_W0SW + PR_W1SW + PR_W2SW + PR_W3SW + PR_WTB + PR_W5B + PR_COPY4)

#define LGKM0() asm volatile("s_waitcnt lgkmcnt(0)" ::: "memory")

__device__ __forceinline__ void gload_lds16(const void* g, void* l) {
    __builtin_amdgcn_global_load_lds(
        (const __attribute__((address_space(1))) void*)g,
        (__attribute__((address_space(3))) void*)l, 16, 0, 0);
}

__global__ __launch_bounds__(256) void prep_kernel(
    const float* __restrict__ W0, const float* __restrict__ W1,
    const float* __restrict__ W2, const float* __restrict__ W3,
    const float* __restrict__ answer, const float* __restrict__ tvec,
    const float* __restrict__ b0,
    bf16* __restrict__ W0sw, bf16* __restrict__ W1sw, bf16* __restrict__ W2sw,
    bf16* __restrict__ W3sw, bf16* __restrict__ WtB, bf16* __restrict__ W5B,
    float* __restrict__ out)
{
    int idx = blockIdx.x * 256 + threadIdx.x;
    if (idx < PR_W0SW) {                 // one chunk-lane per thread: 8 elems
        int lane = idx & 63, c = idx >> 6;
        int fr = lane & 15, quad = lane >> 4;
        int kc = c & 15, iwv = c >> 4;
        bf16 v[8];
        #pragma unroll
        for (int j = 0; j < 8; ++j)
            v[j] = (bf16)W0[(kc * 32 + quad * 8 + j) * 128 + iwv * 16 + fr];
        *(bf16x8*)(W0sw + c * 512 + lane * 8) = *(const bf16x8*)v;
        return;
    }
    idx -= PR_W0SW;
    if (idx < PR_W1SW) {
        int lane = idx & 63, c = idx >> 6;
        int fr = lane & 15, quad = lane >> 4;
        int kc = c & 3, nt = c >> 2;
        bf16 v[8];
        #pragma unroll
        for (int j = 0; j < 8; ++j)
            v[j] = (bf16)W1[(kc * 32 + quad * 8 + j) * 128 + nt * 16 + fr];
        *(bf16x8*)(W1sw + c * 512 + lane * 8) = *(const bf16x8*)v;
        return;
    }
    idx -= PR_W1SW;
    if (idx < PR_W2SW) {
        int lane = idx & 63, c = idx >> 6;
        int fr = lane & 15, quad = lane >> 4;
        int kc = c & 3, nt = c >> 2;
        bf16 v[8];
        #pragma unroll
        for (int j = 0; j < 8; ++j)
            v[j] = (bf16)W2[(kc * 32 + quad * 8 + j) * 128 + nt * 16 + fr];
        *(bf16x8*)(W2sw + c * 512 + lane * 8) = *(const bf16x8*)v;
        return;
    }
    idx -= PR_W2SW;
    if (idx < PR_W3SW) {
        int lane = idx & 63, kc = idx >> 6;
        int fr = lane & 15, quad = lane >> 4;
        bf16 v[8];
        #pragma unroll
        for (int j = 0; j < 8; ++j)
            v[j] = (fr < 2) ? (bf16)W3[(kc * 32 + quad * 8 + j) * 2 + fr] : (bf16)0.0f;
        *(bf16x8*)(W3sw + kc * 512 + lane * 8) = *(const bf16x8*)v;
        return;
    }
    idx -= PR_W3SW;
    if (idx < PR_WTB) {                 // Wt[t][j] = tvec[t]*W0[512][j] + b0[j]
        int t = idx >> 4, s = idx & 15;
        float tv = tvec[t];
        bf16 v[8];
        #pragma unroll
        for (int j = 0; j < 8; ++j)
            v[j] = (bf16)(tv * W0[512 * 128 + s * 8 + j] + b0[s * 8 + j]);
        *(bf16x8*)(WtB + t * 128 + s * 8) = *(const bf16x8*)v;
        return;
    }
    idx -= PR_WTB;
    if (idx < PR_W5B) {                 // W0 rows 513,514,515 -> bf16
        int r = idx >> 4, s = idx & 15;
        bf16 v[8];
        #pragma unroll
        for (int j = 0; j < 8; ++j)
            v[j] = (bf16)W0[(513 + r) * 128 + s * 8 + j];
        *(bf16x8*)(W5B + r * 128 + s * 8) = *(const bf16x8*)v;
        return;
    }
    idx -= PR_W5B;
    if (idx < PR_COPY4) { ((float4*)out)[idx] = ((const float4*)answer)[idx]; }
}

// E_i[n][j] = sum_k enc[n][k]*W0[i*128+k][j]. 256-thread / 64-row blocks.
__global__ __launch_bounds__(256) void prep_e_kernel(
    const float* __restrict__ encoded, const bf16* __restrict__ W0sw,
    bf16* __restrict__ E)
{
    __shared__ bf16 sA[64][136];
    __shared__ bf16 sT[64][40];
    const int tid = threadIdx.x;
    const int row0 = (blockIdx.x >> 2) * 64;
    const int ntb  = blockIdx.x & 3;
    for (int c = tid; c < 2048; c += 256) {      // 64 rows x 32 float4
        int row = c >> 5, seg = c & 31;
        int rr = row0 + row; if (rr >= NN) rr = NN - 1;
        float4 v = *(const float4*)(encoded + (size_t)rr * 128 + seg * 4);
        bf16 pk[4] = {(bf16)v.x, (bf16)v.y, (bf16)v.z, (bf16)v.w};
        *(uint2*)(&sA[row][seg * 4]) = *(const uint2*)pk;
    }
    __syncthreads();                             // sA staged (cross-wave) — only barrier
    const int wv = tid >> 6, lane = tid & 63;
    const int fr = lane & 15, quad = lane >> 4;
    const bf16* aBase = &sA[wv * 16 + fr][quad * 8];
    bf16x8 aFv[4];
    #pragma unroll
    for (int kcc = 0; kcc < 4; ++kcc) aFv[kcc] = *(const bf16x8*)(aBase + kcc * 32);
    const int orow = tid >> 2, oseg = tid & 3;
    #pragma unroll
    for (int i = 0; i < 4; ++i) {
        #pragma unroll
        for (int ntl = 0; ntl < 2; ++ntl) {
            int nt = ntb * 2 + ntl;
            f32x4 acc = {0.f, 0.f, 0.f, 0.f};
            #pragma unroll
            for (int kcc = 0; kcc < 4; ++kcc) {
                bf16x8 bF = *(const bf16x8*)(W0sw + ((size_t)nt * 16 + i * 4 + kcc) * 512 + lane * 8);
                acc = __builtin_amdgcn_mfma_f32_16x16x32_bf16(aFv[kcc], bF, acc, 0, 0, 0);
            }
            #pragma unroll
            for (int reg = 0; reg < 4; ++reg)
                sT[wv * 16 + quad * 4 + reg][ntl * 16 + fr] = (bf16)acc[reg];
        }
        LGKM0();                                 // own sT writes visible to own wave
        bf16x8 ev = *(const bf16x8*)(&sT[orow][oseg * 8]);
        LGKM0();                                 // reads retired before next i's overwrite
        if (row0 + orow < NN)
            *(bf16x8*)(E + ((size_t)i * NN + row0 + orow) * 128 + ntb * 32 + oseg * 8) = ev;
    }
}

// ---------------------------------------------------------------------------
// Main kernel, R18: VALU/stall trim on the R16 structure (74 us baseline).
// (1) ALL intra-wave lgkmcnt(0) fences removed: DS ops complete in-order
//     within a wave, and every fence guarded a same-wave write->read on
//     wave-private LDS (sH/sScr/sNd) — the asm memory-clobber was only
//     serializing the scheduler (blocked cross-layer load hoisting).
// (2) Packed f32x2/f32x4 math in h0 + epilogues (v_pk_fma/add/mul_f32).
// (3) s_setprio(1) around MFMA clusters (waves are phase-diverse post-B1).
// (4) Scatter: div/mod replaced by lane-constant comp mapping.
// Cross-wave sync unchanged: B1 (W1+W3 staged), B2 (W1 reads done),
// B3 (W2 staged) — real barriers, untouched.
// ---------------------------------------------------------------------------
__global__ __launch_bounds__(512, 4) void main_kernel(
    const float* __restrict__ coords, const int* __restrict__ propers,
    const float* __restrict__ b1, const float* __restrict__ b2,
    const float* __restrict__ b3,
    const bf16* __restrict__ E, const bf16* __restrict__ W1sw,
    const bf16* __restrict__ W2sw, const bf16* __restrict__ W3sw,
    const bf16* __restrict__ WtB, const bf16* __restrict__ W5B,
    float* __restrict__ out)
{
    __shared__ __align__(16) bf16 sH[8][16][136];   // per-wave activation tile
    __shared__ __align__(16) bf16 sW[18432];        // 32KB W1/W2 + 4KB W3 frags
    __shared__ float sScr[8][16][6];                // [0..2]=dh, [3..4]=delta
    __shared__ int   sNd[8][8];                     // per-wave {n0,n3} x 4 propers

    const int tid  = threadIdx.x;
    const int wv   = tid >> 6, lane = tid & 63;
    const int fr   = lane & 15, quad = lane >> 4;
    const int pw   = blockIdx.x * PB + wv * 4;      // first proper of this wave

    // ---- stage W1 (32KB) + W3 (4KB) into LDS, async (drained at B1) ----
    {
        const char* g1 = (const char*)W1sw;
        char* l = (char*)&sW[0];
        #pragma unroll
        for (int r2 = 0; r2 < 4; ++r2)
            gload_lds16(g1 + r2 * 8192 + wv * 1024 + lane * 16,
                        l + r2 * 8192 + wv * 1024);
        if (wv < 4)
            gload_lds16((const char*)W3sw + wv * 1024 + lane * 16,
                        l + 32768 + wv * 1024);
    }

    // ---- E gather: proper pw+quad, cols fr*8..fr*8+7 ----
    int4 pv = *(const int4*)(propers + (size_t)(pw + quad) * 4);
    bf16x8 e0 = *(const bf16x8*)(E + ((size_t)0 * NN + pv.x) * 128 + fr * 8);
    bf16x8 e1 = *(const bf16x8*)(E + ((size_t)1 * NN + pv.y) * 128 + fr * 8);
    bf16x8 e2 = *(const bf16x8*)(E + ((size_t)2 * NN + pv.z) * 128 + fr * 8);
    bf16x8 e3 = *(const bf16x8*)(E + ((size_t)3 * NN + pv.w) * 128 + fr * 8);
    if (fr == 0) { sNd[wv][quad * 2] = pv.x; sNd[wv][quad * 2 + 1] = pv.w; }
    bf16x8 w3v = *(const bf16x8*)(W5B + 0 * 128 + fr * 8);
    bf16x8 w4v = *(const bf16x8*)(W5B + 1 * 128 + fr * 8);
    bf16x8 w5v = *(const bf16x8*)(W5B + 2 * 128 + fr * 8);

    // ---- bias preload (overlaps gather latency) ----
    float b1r[8], b2r[8];
    #pragma unroll
    for (int i = 0; i < 8; ++i) {
        b1r[i] = b1[i * 16 + fr];
        b2r[i] = b2[i * 16 + fr];
    }
    float b3r = (fr < 2) ? b3[fr] : 0.0f;

    // ---- geometry: lanes 0..15 each own one of the wave's 16 rows ----
    float snl = 0.f, csl = 1.f, dll = 0.f;
    if (lane < 16) {
        int pp_ = lane >> 2, t = lane & 3;
        int4 pg = *(const int4*)(propers + (size_t)(pw + pp_) * 4);
        const float* c0 = coords + (size_t)pg.x * 12 + t * 3;
        const float* c1 = coords + (size_t)pg.y * 12 + t * 3;
        const float* c2 = coords + (size_t)pg.z * 12 + t * 3;
        const float* c3 = coords + (size_t)pg.w * 12 + t * 3;
        float u1x = c1[0]-c0[0], u1y = c1[1]-c0[1], u1z = c1[2]-c0[2];
        float u2x = c2[0]-c1[0], u2y = c2[1]-c1[1], u2z = c2[2]-c1[2];
        float u3x = c3[0]-c2[0], u3y = c3[1]-c2[1], u3z = c3[2]-c2[2];
        float ax = u1y*u2z - u1z*u2y, ay = u1z*u2x - u1x*u2z, az = u1x*u2y - u1y*u2x;
        float bx = u2y*u3z - u2z*u3y, by = u2z*u3x - u2x*u3z, bz = u2x*u3y - u2y*u3x;
        float u2n = sqrtf(u2x*u2x + u2y*u2y + u2z*u2z);
        float num = u2n * (u1x*bx + u1y*by + u1z*bz);
        float den = ax*bx + ay*by + az*bz;
        float hyp = sqrtf(num*num + den*den);
        if (hyp > 1e-30f) { float ih = 1.0f / hyp; snl = num * ih; csl = den * ih; }
        else { snl = 0.0f; csl = 1.0f; }
        float drx = c0[0]-c3[0], dry = c0[1]-c3[1], drz = c0[2]-c3[2];
        dll = sqrtf(fmaxf(drx*drx + dry*dry + drz*drz, 1e-12f));
        float il = 1.0f / dll;
        sScr[wv][lane][0] = drx * il;
        sScr[wv][lane][1] = dry * il;
        sScr[wv][lane][2] = drz * il;
    }

    // ---- h0 = leaky(g + Wt[t] + sn*w513 + cs*w514 + dl*w515) -> sH[wv] ----
    {
        f32x2 g2[4], w3f2[4], w4f2[4], w5f2[4];
        #pragma unroll
        for (int j = 0; j < 4; ++j) {
            g2[j] = (f32x2){
                (float)e0[2*j]   + (float)e1[2*j]   + (float)e2[2*j]   + (float)e3[2*j],
                (float)e0[2*j+1] + (float)e1[2*j+1] + (float)e2[2*j+1] + (float)e3[2*j+1] };
            w3f2[j] = (f32x2){ (float)w3v[2*j], (float)w3v[2*j+1] };
            w4f2[j] = (f32x2){ (float)w4v[2*j], (float)w4v[2*j+1] };
            w5f2[j] = (f32x2){ (float)w5v[2*j], (float)w5v[2*j+1] };
        }
        #pragma unroll
        for (int t = 0; t < 4; ++t) {
            int r = quad * 4 + t;                         // wave-relative row
            bf16x8 wtv = *(const bf16x8*)(WtB + t * 128 + fr * 8);
            float sn = __shfl(snl, r), cs = __shfl(csl, r), dl = __shfl(dll, r);
            f32x2 sn2 = {sn, sn}, cs2 = {cs, cs}, dl2 = {dl, dl};
            bf16 hv[8];
            #pragma unroll
            for (int j = 0; j < 4; ++j) {
                f32x2 v = g2[j] + (f32x2){ (float)wtv[2*j], (float)wtv[2*j+1] };
                v = sn2 * w3f2[j] + v;
                v = cs2 * w4f2[j] + v;
                v = dl2 * w5f2[j] + v;
                f32x2 lv = v * LEAKY;
                v.x = fmaxf(v.x, lv.x);
                v.y = fmaxf(v.y, lv.y);
                hv[2*j]   = (bf16)v.x;
                hv[2*j+1] = (bf16)v.y;
            }
            *(bf16x8*)(&sH[wv][r][fr * 8]) = *(const bf16x8*)hv;
        }
    }
    __syncthreads();   // B1: W1+W3 staged (vmcnt drained); h0 in sH is wave-local

    // ---- dense layer: A-frags from own sH, B-frags from block-shared LDS.
    //      No fences: same-wave DS ordering is guaranteed by hardware. ----
#define DENSE_LAYER(BR)                                                         \
    {                                                                           \
        bf16x8 aF[4];                                                           \
        const bf16* aRow = &sH[wv][fr][quad * 8];                               \
        _Pragma("unroll")                                                       \
        for (int kc = 0; kc < 4; ++kc)                                          \
            aF[kc] = *(const bf16x8*)(aRow + kc * 32);                          \
        _Pragma("unroll")                                                       \
        for (int hh = 0; hh < 2; ++hh) {                                        \
            f32x4 acc[4];                                                       \
            _Pragma("unroll")                                                   \
            for (int nt = 0; nt < 4; ++nt) acc[nt] = (f32x4){0.f,0.f,0.f,0.f};  \
            __builtin_amdgcn_s_setprio(1);                                      \
            _Pragma("unroll")                                                   \
            for (int kc = 0; kc < 4; ++kc) {                                    \
                _Pragma("unroll")                                               \
                for (int nt = 0; nt < 4; ++nt) {                                \
                    bf16x8 bF = *(const bf16x8*)(sW +                           \
                        ((hh * 4 + nt) * 4 + kc) * 512 + lane * 8);             \
                    acc[nt] = __builtin_amdgcn_mfma_f32_16x16x32_bf16(          \
                        aF[kc], bF, acc[nt], 0, 0, 0);                          \
                }                                                               \
            }                                                                   \
            __builtin_amdgcn_s_setprio(0);                                      \
            _Pragma("unroll")                                                   \
            for (int nt = 0; nt < 4; ++nt) {                                    \
                int j = (hh * 4 + nt) * 16 + fr;                                \
                f32x4 v = acc[nt] + BR[hh * 4 + nt];                            \
                f32x4 lv = v * LEAKY;                                           \
                v.x = fmaxf(v.x, lv.x); v.y = fmaxf(v.y, lv.y);                 \
                v.z = fmaxf(v.z, lv.z); v.w = fmaxf(v.w, lv.w);                 \
                _Pragma("unroll")                                               \
                for (int reg = 0; reg < 4; ++reg)                               \
                    sH[wv][quad * 4 + reg][j] = (bf16)v[reg];                   \
            }                                                                   \
        }                                                                       \
    }

    DENSE_LAYER(b1r)           // h1 = leaky(h0 @ W1 + b1), in place
    __syncthreads();           // B2: all waves done reading W1 frags
    {                          // stage W2 over W1 (async, drained at B3)
        const char* g2 = (const char*)W2sw;
        char* l = (char*)&sW[0];
        #pragma unroll
        for (int r2 = 0; r2 < 4; ++r2)
            gload_lds16(g2 + r2 * 8192 + wv * 1024 + lane * 16,
                        l + r2 * 8192 + wv * 1024);
    }
    __syncthreads();           // B3: W2 staged
    DENSE_LAYER(b2r)           // h2 = leaky(h1 @ W2 + b2), in place

    // ---- delta = h2 @ W3 + b3 (zero-padded to 16 cols); W3 frags at sW+16384 ----
    {
        bf16x8 aF[4];
        const bf16* aRow = &sH[wv][fr][quad * 8];
        #pragma unroll
        for (int kc = 0; kc < 4; ++kc)
            aF[kc] = *(const bf16x8*)(aRow + kc * 32);
        f32x4 dacc = {0.f, 0.f, 0.f, 0.f};
        __builtin_amdgcn_s_setprio(1);
        #pragma unroll
        for (int kc = 0; kc < 4; ++kc) {
            bf16x8 bF = *(const bf16x8*)(sW + 16384 + kc * 512 + lane * 8);
            dacc = __builtin_amdgcn_mfma_f32_16x16x32_bf16(aF[kc], bF, dacc, 0, 0, 0);
        }
        __builtin_amdgcn_s_setprio(0);
        if (fr < 2) {
            #pragma unroll
            for (int reg = 0; reg < 4; ++reg)
                sScr[wv][quad * 4 + reg][3 + fr] = dacc[reg] + b3r;
        }
    }

    // ---- scatter-add: 16 rows x 6 comps = 96 items; comp = lane>>4 based,
    //      no div/mod. Same-wave DS ordering makes delta/dh/sNd visible. ----
    {
        int row = lane & 15;
        int comp = lane >> 4;                      // 0..3
        int side = (comp == 3) ? 1 : 0;
        int ax = side ? 0 : comp;
        int node = sNd[wv][(row >> 2) * 2 + side];
        float dval = (side ? 0.5f : -0.5f) * sScr[wv][row][3 + side];
        atomicAdd(out + (size_t)node * 12 + (row & 3) * 3 + ax, dval * sScr[wv][row][ax]);
        if (lane < 32) {                           // comps 4,5: side 1, ax 1,2
            int ax2 = 1 + comp;                    // comp is 0 or 1 here
            int node2 = sNd[wv][(row >> 2) * 2 + 1];
            float dval2 = 0.5f * sScr[wv][row][4];
            atomicAdd(out + (size_t)node2 * 12 + (row & 3) * 3 + ax2, dval2 * sScr[wv][row][ax2]);
        }
    }
#undef DENSE_LAYER
}

extern "C" void kernel_launch(void* const* d_in, const int* in_sizes, int n_in,
                              void* d_out, int out_size, void* d_ws, size_t ws_size,
                              hipStream_t stream) {
    const float* coords  = (const float*)d_in[0];
    const int*   propers = (const int*)d_in[1];
    const float* encoded = (const float*)d_in[2];
    const float* tvec    = (const float*)d_in[3];
    const float* answer  = (const float*)d_in[4];
    const float* W0 = (const float*)d_in[5];
    const float* b0 = (const float*)d_in[6];
    const float* W1 = (const float*)d_in[7];
    const float* b1 = (const float*)d_in[8];
    const float* W2 = (const float*)d_in[9];
    const float* b2 = (const float*)d_in[10];
    const float* W3 = (const float*)d_in[11];
    const float* b3 = (const float*)d_in[12];
    float* out = (float*)d_out;
    char* ws = (char*)d_ws;
    bf16* W0sw = (bf16*)(ws + OFF_W0SW);
    bf16* W1sw = (bf16*)(ws + OFF_W1SW);
    bf16* W2sw = (bf16*)(ws + OFF_W2SW);
    bf16* W3sw = (bf16*)(ws + OFF_W3SW);
    bf16* WtB  = (bf16*)(ws + OFF_WTB);
    bf16* W5B  = (bf16*)(ws + OFF_W5B);
    bf16* E    = (bf16*)(ws + OFF_E);

    int prep_blocks = (PR_TOTAL + 255) / 256;
    prep_kernel<<<prep_blocks, 256, 0, stream>>>(W0, W1, W2, W3, answer, tvec, b0,
                                                 W0sw, W1sw, W2sw, W3sw, WtB, W5B, out);
    prep_e_kernel<<<391 * 4, 256, 0, stream>>>(encoded, W0sw, E);
    main_kernel<<<PP / PB, 512, 0, stream>>>(coords, propers, b1, b2, b3,
                                             E, W1sw, W2sw, W3sw, WtB, W5B, out);
}